// Round 1
// baseline (1455.593 us; speedup 1.0000x reference)
//
#include <hip/hip_runtime.h>

// Problem constants (setup_inputs: B=16, C=256, H=W=224, p=14)
#define BB  16
#define CC  256
#define HH  224
#define WW  224
#define PP  14
#define NHH 16
#define NWW 16
#define NN  256   // NHH*NWW patches per image

// ---------------------------------------------------------------------------
// Kernel 1: per-(b,c) slice, compute partial dot(t_n, q), ||t_n||^2, ||q||^2.
// One block per (b,c); thread w owns image column w (coalesced row reads).
// ---------------------------------------------------------------------------
__global__ __launch_bounds__(256) void partials_kernel(
    const float* __restrict__ qf, const float* __restrict__ rf,
    const int* __restrict__ click,
    float* __restrict__ dotp, float* __restrict__ tn2, float* __restrict__ qn2)
{
    const int bc  = blockIdx.x;
    const int b   = bc >> 8;      // / CC
    const int c   = bc & 255;     // % CC
    const int tid = threadIdx.x;

    __shared__ float qs[PP * PP];   // query sub-patch for this (b,c)
    __shared__ float reda[WW];
    __shared__ float redb[WW];
    __shared__ float dots[NN];
    __shared__ float nrms[NN];

    const int qh = click[2 * b + 1] / PP;   // y -> patch row
    const int qw = click[2 * b + 0] / PP;   // x -> patch col

    const size_t slice = (size_t)(b * CC + c) * (HH * WW);

    // Stage query sub-patch (14x14) into LDS; accumulate its squared norm.
    float qsq = 0.f;
    if (tid < PP * PP) {
        const int ph = tid / PP;
        const int pw = tid - ph * PP;
        const float v = qf[slice + (size_t)(qh * PP + ph) * WW + qw * PP + pw];
        qs[tid] = v;
        qsq = v * v;
    }
    __syncthreads();

    // ||q||^2 partial: wave reduce, one global atomic per wave.
    #pragma unroll
    for (int off = 32; off > 0; off >>= 1)
        qsq += __shfl_down(qsq, off, 64);
    if ((tid & 63) == 0)
        atomicAdd(&qn2[b], qsq);

    const int  w   = tid;
    const bool act = (w < WW);
    int j = 0, pw = 0;
    float qr[PP];
    const float* colp = rf + slice + w;
    if (act) {
        j  = w / PP;
        pw = w - j * PP;
        #pragma unroll
        for (int ph = 0; ph < PP; ++ph) qr[ph] = qs[ph * PP + pw];
    }

    for (int i = 0; i < NHH; ++i) {
        float ad = 0.f, an = 0.f;
        if (act) {
            const float* rp = colp + (size_t)i * PP * WW;
            #pragma unroll
            for (int ph = 0; ph < PP; ++ph) {
                const float v = rp[(size_t)ph * WW];
                ad = fmaf(v, qr[ph], ad);
                an = fmaf(v, v, an);
            }
            reda[w] = ad;
            redb[w] = an;
        }
        __syncthreads();
        if (tid < NWW) {
            float sd = 0.f, sn = 0.f;
            #pragma unroll
            for (int k = 0; k < PP; ++k) {
                sd += reda[tid * PP + k];
                sn += redb[tid * PP + k];
            }
            dots[i * NWW + tid] = sd;
            nrms[i * NWW + tid] = sn;
        }
        __syncthreads();
    }

    // One atomic per patch per block (sum over c happens via atomics).
    atomicAdd(&dotp[b * NN + tid], dots[tid]);
    atomicAdd(&tn2[b * NN + tid],  nrms[tid]);
}

// ---------------------------------------------------------------------------
// Kernel 2: cosine sim -> L2-normalize sim -> log_softmax -> mean NLL.
// Single block, 256 threads (one per patch), loops over B.
// ---------------------------------------------------------------------------
__global__ __launch_bounds__(256) void finalize_kernel(
    const float* __restrict__ dotp, const float* __restrict__ tn2,
    const float* __restrict__ qn2, const float* __restrict__ scale_p,
    const int* __restrict__ gt, float* __restrict__ out)
{
    const int tid = threadIdx.x;
    __shared__ float red[NN];
    __shared__ float slog;
    const float scale = scale_p[0];
    float total = 0.f;

    for (int b = 0; b < BB; ++b) {
        const float qn  = fmaxf(sqrtf(qn2[b]), 1e-8f);                 // EPS_COS
        const float tn  = fmaxf(sqrtf(tn2[b * NN + tid]), 1e-8f);
        const float sim = dotp[b * NN + tid] / (tn * qn);

        // sum of sim^2 over the N patches
        red[tid] = sim * sim;
        __syncthreads();
        for (int s = 128; s > 0; s >>= 1) {
            if (tid < s) red[tid] += red[tid + s];
            __syncthreads();
        }
        const float denom = fmaxf(sqrtf(red[0]), 1e-12f);              // EPS_NORM
        __syncthreads();

        const float logit = scale * sim / denom;

        // max-reduce
        red[tid] = logit;
        __syncthreads();
        for (int s = 128; s > 0; s >>= 1) {
            if (tid < s) red[tid] = fmaxf(red[tid], red[tid + s]);
            __syncthreads();
        }
        const float m = red[0];
        __syncthreads();

        // sum-exp reduce
        red[tid] = expf(logit - m);
        __syncthreads();
        for (int s = 128; s > 0; s >>= 1) {
            if (tid < s) red[tid] += red[tid + s];
            __syncthreads();
        }
        const float lse = m + logf(red[0]);

        const int label = (gt[2 * b + 1] / PP) * NWW + (gt[2 * b + 0] / PP);
        if (tid == label) slog = logit;
        __syncthreads();
        total += lse - slog;
        __syncthreads();   // protect red/slog before next iteration
    }

    if (tid == 0) out[0] = total * (1.0f / BB);
}

extern "C" void kernel_launch(void* const* d_in, const int* in_sizes, int n_in,
                              void* d_out, int out_size, void* d_ws, size_t ws_size,
                              hipStream_t stream) {
    const float* qf      = (const float*)d_in[0];
    const float* rf      = (const float*)d_in[1];
    const float* scale_p = (const float*)d_in[2];
    const int*   click   = (const int*)d_in[3];
    const int*   gt      = (const int*)d_in[4];
    // d_in[5] = patch_size (14) — baked into constants above.

    float* dotp = (float*)d_ws;          // [BB*NN]
    float* tn2  = dotp + BB * NN;        // [BB*NN]
    float* qn2  = tn2 + BB * NN;         // [BB]
    const size_t zbytes = (size_t)(2 * BB * NN + BB) * sizeof(float);
    hipMemsetAsync(d_ws, 0, zbytes, stream);

    partials_kernel<<<BB * CC, 256, 0, stream>>>(qf, rf, click, dotp, tn2, qn2);
    finalize_kernel<<<1, 256, 0, stream>>>(dotp, tn2, qn2, scale_p, gt, (float*)d_out);
}